// Round 1
// baseline (12010.968 us; speedup 1.0000x reference)
//
#include <hip/hip_runtime.h>

// ---------------- problem constants ----------------
#define S_LEN 512
#define B_SZ  64
#define E_DIM 512
#define H_DIM 512
#define K_DIM 1024
#define NWG   64
#define COLS  48          // gate-cols per WG = 6 gates * 8 h-cols
#define OUT_ALLH (S_LEN*B_SZ*H_DIM)          // 16777216
#define OUT_SH   (OUT_ALLH)                  // state_hidden offset (floats)
#define OUT_SC   (OUT_ALLH + B_SZ*H_DIM)     // state_context offset

// ---------------- ws layout (bytes) ----------------
#define O_WT    0ull
#define SZ_WT   (3072ull*1024*2)             // bf16 [3072][1024]  (row n = q*512+col)
#define O_BIAS  (O_WT + SZ_WT)
#define SZ_BIAS (3072ull*4)
#define O_HBF   (O_BIAS + SZ_BIAS)
#define SZ_HBF  (2ull*64*512*2)              // bf16 double buffer [2][64][512]
#define O_FLAGH (O_HBF + SZ_HBF)
#define O_FLAGP (O_FLAGH + 256)
#define O_P     (O_FLAGP + 256)
#define SZ_P    (64ull*2*64*4)               // [wg][gate][row] f32 partial sums
#define O_XBF   (O_P + SZ_P)
#define SZ_XBF  (512ull*64*512*2)            // bf16 copy of embedded_tokens
#define WS_FULL (O_XBF + SZ_XBF)

// ---------------- LDS layout (bytes) ----------------
#define L_WLDS  0                // 48*1024 bf16 swizzled         = 98304
#define L_ZLDS  98304            // 64*256  bf16 swizzled         = 32768
#define L_GATES 131072           // 64*52 f32                     = 13312
#define L_CST   144384           // 64*8  f32                     = 2048
#define L_BLDS  146432           // 48 f32                        = 192
#define L_SLEN  146624           // 64 int                        = 256
#define SMEM_TOTAL 146880

typedef short bf16x8 __attribute__((ext_vector_type(8)));
typedef float f32x4  __attribute__((ext_vector_type(4)));

__device__ __forceinline__ unsigned short f2bf(float f) {
  unsigned u = __float_as_uint(f);
  u += 0x7fffu + ((u >> 16) & 1u);     // round-to-nearest-even
  return (unsigned short)(u >> 16);
}

// ---------------- prep: transpose weights to bf16 [n=q*512+col][k], biases, Hbf[1]=h0, zero flags ----------------
struct PrepArgs {
  const float* W[6]; const float* bia[6];
  const float* h0;
  unsigned short* WT; float* bias_all; unsigned short* Hbf;
  int* flagH; int* flagP;
};

__global__ void prep_kernel(PrepArgs a) {
  const int n = blockIdx.x, tid = threadIdx.x;
  if (n < 3072) {
    const int q = n >> 9, col = n & 511;
    const float* Wq = a.W[q];
    for (int k = tid; k < 1024; k += 256)
      a.WT[(size_t)n*1024 + k] = f2bf(Wq[k*512 + col]);
    if (tid == 0) a.bias_all[n] = a.bia[q][col];
  } else if (n < 3136) {
    const int b = n - 3072;
    for (int h = tid; h < 512; h += 256)
      a.Hbf[(size_t)(64 + b)*512 + h] = f2bf(a.h0[b*512 + h]);   // Hbf[1] = h_{-1}
  } else {
    if (tid < 64) a.flagH[tid] = 0;
    else if (tid < 128) a.flagP[tid - 64] = 0;
  }
}

// ---------------- convert X to bf16 ----------------
__global__ void convx_kernel(const float* __restrict__ x, unsigned short* __restrict__ xbf) {
  const size_t i = ((size_t)blockIdx.x*256 + threadIdx.x) * 4;
  float4 v = *(const float4*)(x + i);
  ushort4 r;
  r.x = f2bf(v.x); r.y = f2bf(v.y); r.z = f2bf(v.z); r.w = f2bf(v.w);
  *(ushort4*)(xbf + i) = r;
}

// ---------------- persistent recurrent kernel ----------------
struct LstmArgs {
  const float* x; const unsigned short* xbf; const float* c0; const int* slen;
  const unsigned short* WT; const float* bias_all; unsigned short* Hbf;
  int* flagH; int* flagP; float* P; float* out;
};

__launch_bounds__(256)
__global__ void lstm_kernel(LstmArgs a) {
  extern __shared__ char smem[];
  char*  wlds  = smem + L_WLDS;
  char*  zlds  = smem + L_ZLDS;
  float* gates = (float*)(smem + L_GATES);
  float* cst   = (float*)(smem + L_CST);
  float* blds  = (float*)(smem + L_BLDS);
  int*   slenl = (int*)(smem + L_SLEN);

  const int wg = blockIdx.x, tid = threadIdx.x;
  const int lane = tid & 63, wv = tid >> 6;
  const bool ux = (a.xbf != nullptr);

  // ---- one-time init: weights (swizzled), biases, seq_lengths, c0 slice ----
  for (int m = tid; m < COLS*128; m += 256) {
    const int col = m >> 7, kc = m & 127;
    const int q = col >> 3, c = col & 7;
    uint4 v = *(const uint4*)(a.WT + ((size_t)(q*512 + wg*8 + c))*1024 + kc*8);
    *(uint4*)(wlds + col*2048 + ((kc ^ (col & 7)) << 4)) = v;
  }
  if (tid < COLS) { const int q = tid >> 3, c = tid & 7; blds[tid] = a.bias_all[q*512 + wg*8 + c]; }
  if (tid < 64) slenl[tid] = a.slen[tid];
  for (int e = tid; e < 512; e += 256) { const int r = e >> 3, c = e & 7; cst[e] = a.c0[r*512 + wg*8 + c]; }
  __syncthreads();

  for (int t = 0; t < S_LEN; ++t) {
    f32x4 acc[3] = { f32x4{0,0,0,0}, f32x4{0,0,0,0}, f32x4{0,0,0,0} };

    // K split into 4 quarters: kh 0,1 = x-part (no dependency), kh 2,3 = h-part (needs flagH >= t)
    for (int kh = 0; kh < 4; ++kh) {
      if (kh == 2) {
        if (tid < 64) {
          while (__hip_atomic_load(&a.flagH[tid], __ATOMIC_RELAXED, __HIP_MEMORY_SCOPE_AGENT) < t)
            __builtin_amdgcn_s_sleep(1);
        }
      }
      __syncthreads();
      if (kh == 2) __builtin_amdgcn_fence(__ATOMIC_ACQUIRE, "agent");

      // stage zlds quarter: 64 rows x 32 chunks(16B)
      #pragma unroll
      for (int j = 0; j < 8; ++j) {
        const int m = tid + j*256;
        const int row = m >> 5, kc = m & 31;
        char* dst = zlds + row*512 + ((kc ^ (row & 7)) << 4);
        if (kh < 2) {
          const size_t off = ((size_t)t*64 + row)*512 + kh*256 + kc*8;
          if (ux) {
            *(uint4*)dst = *(const uint4*)(a.xbf + off);
          } else {
            const float* sp = a.x + off;
            float4 v0 = *(const float4*)(sp);
            float4 v1 = *(const float4*)(sp + 4);
            bf16x8 r;
            r[0]=(short)f2bf(v0.x); r[1]=(short)f2bf(v0.y); r[2]=(short)f2bf(v0.z); r[3]=(short)f2bf(v0.w);
            r[4]=(short)f2bf(v1.x); r[5]=(short)f2bf(v1.y); r[6]=(short)f2bf(v1.z); r[7]=(short)f2bf(v1.w);
            *(bf16x8*)dst = r;
          }
        } else {
          const size_t off = ((size_t)(((t+1)&1)*64 + row))*512 + (kh-2)*256 + kc*8;
          *(uint4*)dst = *(const uint4*)(a.Hbf + off);
        }
      }
      __syncthreads();

      // MFMA over this K-quarter: 8 k-steps x 3 n-tiles
      #pragma unroll
      for (int kt = 0; kt < 8; ++kt) {
        const int arow = wv*16 + (lane & 15);
        const int akc  = kt*4 + (lane >> 4);
        bf16x8 af = *(const bf16x8*)(zlds + arow*512 + ((akc ^ (arow & 7)) << 4));
        #pragma unroll
        for (int nt = 0; nt < 3; ++nt) {
          const int bcol = nt*16 + (lane & 15);
          const int bkc  = kh*32 + kt*4 + (lane >> 4);
          bf16x8 bfr = *(const bf16x8*)(wlds + bcol*2048 + ((bkc ^ (bcol & 7)) << 4));
          acc[nt] = __builtin_amdgcn_mfma_f32_16x16x32_bf16(af, bfr, acc[nt], 0, 0, 0);
        }
      }
    }

    // ---- dump accumulators to LDS gates [row][48] (stride 52) ----
    #pragma unroll
    for (int nt = 0; nt < 3; ++nt)
      #pragma unroll
      for (int ri = 0; ri < 4; ++ri) {
        const int row = wv*16 + (lane >> 4)*4 + ri;
        gates[row*52 + nt*16 + (lane & 15)] = acc[nt][ri];
      }
    __syncthreads();

    // ---- softmax partial sums for mf (q=4) / mi (q=5); exp stored back ----
    if (tid < 128) {
      const int gi = tid >> 6, r = tid & 63;
      float s = 0.f;
      #pragma unroll
      for (int c = 0; c < 8; ++c) {
        float e = __expf(gates[r*52 + (4+gi)*8 + c] + blds[(4+gi)*8 + c]);
        gates[r*52 + (4+gi)*8 + c] = e;
        s += e;
      }
      a.P[((size_t)wg*2 + gi)*64 + r] = s;
    }
    __syncthreads();
    if (tid == 0) {
      __builtin_amdgcn_fence(__ATOMIC_RELEASE, "agent");
      __hip_atomic_store(&a.flagP[wg], t+1, __ATOMIC_RELAXED, __HIP_MEMORY_SCOPE_AGENT);
    }
    if (tid < 64) {
      while (__hip_atomic_load(&a.flagP[tid], __ATOMIC_RELAXED, __HIP_MEMORY_SCOPE_AGENT) < t+1)
        __builtin_amdgcn_s_sleep(1);
    }
    __syncthreads();
    __builtin_amdgcn_fence(__ATOMIC_ACQUIRE, "agent");

    // ---- prefix over WGs + local cumsum -> final mf/mi in gates ----
    if (tid < 128) {
      const int gi = tid >> 6, r = tid & 63;
      float off = 0.f, tot = 0.f;
      for (int s2 = 0; s2 < 64; ++s2) {
        float v = a.P[((size_t)s2*2 + gi)*64 + r];
        tot += v;
        if (s2 < wg) off += v;
      }
      const float inv = 1.f / tot;
      float run = off;
      #pragma unroll
      for (int c = 0; c < 8; ++c) {
        run += gates[r*52 + (4+gi)*8 + c];
        gates[r*52 + (4+gi)*8 + c] = run * inv;
      }
    }
    __syncthreads();

    // ---- elementwise update: c,h; write all_h, Hbf, states ----
    for (int e = tid; e < 512; e += 256) {
      const int r = e >> 3, c = e & 7;
      const float* g = gates + r*52;
      const float fp = g[c]      + blds[c];
      const float ip = g[8 + c]  + blds[8 + c];
      const float op = g[16 + c] + blds[16 + c];
      const float cp = g[24 + c] + blds[24 + c];
      const float mf = g[32 + c];
      const float mi = g[40 + c];
      const float ft = 1.f / (1.f + __expf(-fp));
      const float it = 1.f / (1.f + __expf(-ip));
      const float ot = 1.f / (1.f + __expf(-op));
      const float ch = tanhf(cp);
      const float w2 = mf * mi;
      const float fh = ft * w2 + (mf - w2);
      const float ih = it * w2 + (mi - w2);
      const float cn = fh * cst[e] + ih * ch;
      cst[e] = cn;
      const float h = ot * cn;
      const int col = wg*8 + c;
      a.out[(size_t)t*32768 + r*512 + col] = h;
      a.Hbf[(size_t)((t & 1)*64 + r)*512 + col] = f2bf(h);
      if (t == slenl[r] - 1) {
        a.out[(size_t)OUT_SH + r*512 + col] = h;
        a.out[(size_t)OUT_SC + r*512 + col] = cn;
      }
    }
    __syncthreads();
    if (tid == 0) {
      __builtin_amdgcn_fence(__ATOMIC_RELEASE, "agent");
      __hip_atomic_store(&a.flagH[wg], t+1, __ATOMIC_RELAXED, __HIP_MEMORY_SCOPE_AGENT);
    }
  }
}

// ---------------- host ----------------
extern "C" void kernel_launch(void* const* d_in, const int* in_sizes, int n_in,
                              void* d_out, int out_size, void* d_ws, size_t ws_size,
                              hipStream_t stream) {
  char* ws = (char*)d_ws;

  PrepArgs pa;
  for (int q = 0; q < 6; ++q) {
    pa.W[q]   = (const float*)d_in[3 + 2*q];
    pa.bia[q] = (const float*)d_in[4 + 2*q];
  }
  pa.h0       = (const float*)d_in[1];
  pa.WT       = (unsigned short*)(ws + O_WT);
  pa.bias_all = (float*)(ws + O_BIAS);
  pa.Hbf      = (unsigned short*)(ws + O_HBF);
  pa.flagH    = (int*)(ws + O_FLAGH);
  pa.flagP    = (int*)(ws + O_FLAGP);
  prep_kernel<<<3137, 256, 0, stream>>>(pa);

  const bool ux = (ws_size >= WS_FULL);
  if (ux)
    convx_kernel<<<16384, 256, 0, stream>>>((const float*)d_in[0], (unsigned short*)(ws + O_XBF));

  LstmArgs la;
  la.x        = (const float*)d_in[0];
  la.xbf      = ux ? (const unsigned short*)(ws + O_XBF) : nullptr;
  la.c0       = (const float*)d_in[2];
  la.slen     = (const int*)d_in[15];
  la.WT       = pa.WT;
  la.bias_all = pa.bias_all;
  la.Hbf      = pa.Hbf;
  la.flagH    = pa.flagH;
  la.flagP    = pa.flagP;
  la.P        = (float*)(ws + O_P);
  la.out      = (float*)d_out;

  hipFuncSetAttribute(reinterpret_cast<const void*>(lstm_kernel),
                      hipFuncAttributeMaxDynamicSharedMemorySize, SMEM_TOTAL);
  lstm_kernel<<<NWG, 256, SMEM_TOTAL, stream>>>(la);
}

// Round 2
// 8145.161 us; speedup vs baseline: 1.4746x; 1.4746x over previous
//
#include <hip/hip_runtime.h>

// ---------------- problem constants ----------------
#define S_LEN 512
#define B_SZ  64
#define E_DIM 512
#define H_DIM 512
#define K_DIM 1024
#define NWG   64
#define COLS  48          // gate-cols per WG = 6 gates * 8 h-cols
#define OUT_ALLH (S_LEN*B_SZ*H_DIM)          // 16777216
#define OUT_SH   (OUT_ALLH)                  // state_hidden offset (floats)
#define OUT_SC   (OUT_ALLH + B_SZ*H_DIM)     // state_context offset

// ---------------- ws layout (bytes) ----------------
#define O_WT    0ull
#define SZ_WT   (3072ull*1024*2)             // bf16 [3072][1024]  (row n = q*512+col)
#define O_BIAS  (O_WT + SZ_WT)
#define SZ_BIAS (3072ull*4)
#define O_HBF   (O_BIAS + SZ_BIAS)
#define SZ_HBF  (2ull*64*512*2)              // bf16 double buffer [2][64][512]
#define O_FLAGH (O_HBF + SZ_HBF)
#define O_FLAGP (O_FLAGH + 256)
#define O_P     (O_FLAGP + 256)
#define SZ_P    (2ull*64*64*4)               // [gate][row][wg] f32 partial sums
#define O_XBF   (O_P + SZ_P)
#define SZ_XBF  (512ull*64*512*2)            // bf16 copy of embedded_tokens
#define WS_FULL (O_XBF + SZ_XBF)

// ---------------- LDS layout (bytes) ----------------
#define L_WLDS  0                // 48*1024 bf16 swizzled         = 98304
#define L_ZLDS  98304            // 64*256  bf16 swizzled         = 32768
#define L_GATES 131072           // 64*52 f32                     = 13312
#define L_CST   144384           // 64*8  f32                     = 2048
#define L_BLDS  146432           // 48 f32                        = 192
#define L_SLEN  146624           // 64 int                        = 256
#define SMEM_TOTAL 146880

typedef short bf16x8 __attribute__((ext_vector_type(8)));
typedef float f32x4  __attribute__((ext_vector_type(4)));

__device__ __forceinline__ unsigned short f2bf(float f) {
  unsigned u = __float_as_uint(f);
  u += 0x7fffu + ((u >> 16) & 1u);     // round-to-nearest-even
  return (unsigned short)(u >> 16);
}

#define ATOM_LD(p)    __hip_atomic_load((p), __ATOMIC_RELAXED, __HIP_MEMORY_SCOPE_AGENT)
#define ATOM_ST(p, v) __hip_atomic_store((p), (v), __ATOMIC_RELAXED, __HIP_MEMORY_SCOPE_AGENT)

// ---------------- prep: transpose weights to bf16 [n=q*512+col][k], biases, Hbf[1]=h0, zero flags ----------------
struct PrepArgs {
  const float* W[6]; const float* bia[6];
  const float* h0;
  unsigned short* WT; float* bias_all; unsigned short* Hbf;
  int* flagH; int* flagP;
};

__global__ void prep_kernel(PrepArgs a) {
  const int n = blockIdx.x, tid = threadIdx.x;
  if (n < 3072) {
    const int q = n >> 9, col = n & 511;
    const float* Wq = a.W[q];
    for (int k = tid; k < 1024; k += 256)
      a.WT[(size_t)n*1024 + k] = f2bf(Wq[k*512 + col]);
    if (tid == 0) a.bias_all[n] = a.bia[q][col];
  } else if (n < 3136) {
    const int b = n - 3072;
    for (int h = tid; h < 512; h += 256)
      a.Hbf[(size_t)(64 + b)*512 + h] = f2bf(a.h0[b*512 + h]);   // Hbf[1] = h_{-1}
  } else {
    if (tid < 64) a.flagH[tid] = 0;
    else if (tid < 128) a.flagP[tid - 64] = 0;
  }
}

// ---------------- convert X to bf16 ----------------
__global__ void convx_kernel(const float* __restrict__ x, unsigned short* __restrict__ xbf) {
  const size_t i = ((size_t)blockIdx.x*256 + threadIdx.x) * 4;
  float4 v = *(const float4*)(x + i);
  ushort4 r;
  r.x = f2bf(v.x); r.y = f2bf(v.y); r.z = f2bf(v.z); r.w = f2bf(v.w);
  *(ushort4*)(xbf + i) = r;
}

// ---------------- persistent recurrent kernel ----------------
struct LstmArgs {
  const float* x; const unsigned short* xbf; const float* c0; const int* slen;
  const unsigned short* WT; const float* bias_all; unsigned short* Hbf;
  int* flagH; int* flagP; float* P; float* out;
};

__launch_bounds__(256)
__global__ void lstm_kernel(LstmArgs a) {
  extern __shared__ char smem[];
  char*  wlds  = smem + L_WLDS;
  char*  zlds  = smem + L_ZLDS;
  float* gates = (float*)(smem + L_GATES);
  float* cst   = (float*)(smem + L_CST);
  float* blds  = (float*)(smem + L_BLDS);
  int*   slenl = (int*)(smem + L_SLEN);

  const int wg = blockIdx.x, tid = threadIdx.x;
  const int lane = tid & 63, wv = tid >> 6;
  const bool ux = (a.xbf != nullptr);

  // ---- one-time init: weights (swizzled), biases, seq_lengths, c0 slice ----
  for (int m = tid; m < COLS*128; m += 256) {
    const int col = m >> 7, kc = m & 127;
    const int q = col >> 3, c = col & 7;
    uint4 v = *(const uint4*)(a.WT + ((size_t)(q*512 + wg*8 + c))*1024 + kc*8);
    *(uint4*)(wlds + col*2048 + ((kc ^ (col & 7)) << 4)) = v;
  }
  if (tid < COLS) { const int q = tid >> 3, c = tid & 7; blds[tid] = a.bias_all[q*512 + wg*8 + c]; }
  if (tid < 64) slenl[tid] = a.slen[tid];
  for (int e = tid; e < 512; e += 256) { const int r = e >> 3, c = e & 7; cst[e] = a.c0[r*512 + wg*8 + c]; }
  __syncthreads();

  for (int t = 0; t < S_LEN; ++t) {
    f32x4 acc[3] = { f32x4{0,0,0,0}, f32x4{0,0,0,0}, f32x4{0,0,0,0} };

    // K split into 4 quarters: kh 0,1 = x-part (no dependency), kh 2,3 = h-part (needs flagH >= t)
    for (int kh = 0; kh < 4; ++kh) {
      if (kh == 2) {
        if (tid < 64) {
          while (ATOM_LD(&a.flagH[tid]) < t)
            __builtin_amdgcn_s_sleep(1);
        }
      }
      __syncthreads();

      // stage zlds quarter
      if (kh < 2) {
        // x part: 64 rows x 32 chunks(16B), plain (read-only data, kernel-boundary coherent)
        #pragma unroll
        for (int j = 0; j < 8; ++j) {
          const int m = tid + j*256;
          const int row = m >> 5, kc = m & 31;
          char* dst = zlds + row*512 + ((kc ^ (row & 7)) << 4);
          if (ux) {
            const size_t off = ((size_t)t*64 + row)*512 + kh*256 + kc*8;
            *(uint4*)dst = *(const uint4*)(a.xbf + off);
          } else {
            const size_t off = ((size_t)t*64 + row)*512 + kh*256 + kc*8;
            const float* sp = a.x + off;
            float4 v0 = *(const float4*)(sp);
            float4 v1 = *(const float4*)(sp + 4);
            bf16x8 r;
            r[0]=(short)f2bf(v0.x); r[1]=(short)f2bf(v0.y); r[2]=(short)f2bf(v0.z); r[3]=(short)f2bf(v0.w);
            r[4]=(short)f2bf(v1.x); r[5]=(short)f2bf(v1.y); r[6]=(short)f2bf(v1.z); r[7]=(short)f2bf(v1.w);
            *(bf16x8*)dst = r;
          }
        }
      } else {
        // h part: cross-WG data -> agent-scope atomic 8B loads (bypass stale L2, read IF$)
        // issue all 16 loads first, then write LDS, so they stay pipelined
        unsigned long long tmp[16];
        #pragma unroll
        for (int j = 0; j < 16; ++j) {
          const int idx = tid + j*256;             // 0..4095 8B-chunks
          const int row = idx >> 6, k8 = idx & 63;
          const size_t off = ((size_t)(((t+1)&1)*64 + row))*512 + (size_t)(kh-2)*256 + (size_t)k8*4;
          tmp[j] = ATOM_LD((const unsigned long long*)(a.Hbf + off));
        }
        #pragma unroll
        for (int j = 0; j < 16; ++j) {
          const int idx = tid + j*256;
          const int row = idx >> 6, k8 = idx & 63;
          const int kc = k8 >> 1, half = k8 & 1;
          *(unsigned long long*)(zlds + row*512 + ((kc ^ (row & 7)) << 4) + half*8) = tmp[j];
        }
      }
      __syncthreads();

      // MFMA over this K-quarter: 8 k-steps x 3 n-tiles
      #pragma unroll
      for (int kt = 0; kt < 8; ++kt) {
        const int arow = wv*16 + (lane & 15);
        const int akc  = kt*4 + (lane >> 4);
        bf16x8 af = *(const bf16x8*)(zlds + arow*512 + ((akc ^ (arow & 7)) << 4));
        #pragma unroll
        for (int nt = 0; nt < 3; ++nt) {
          const int bcol = nt*16 + (lane & 15);
          const int bkc  = kh*32 + kt*4 + (lane >> 4);
          bf16x8 bfr = *(const bf16x8*)(wlds + bcol*2048 + ((bkc ^ (bcol & 7)) << 4));
          acc[nt] = __builtin_amdgcn_mfma_f32_16x16x32_bf16(af, bfr, acc[nt], 0, 0, 0);
        }
      }
    }

    // ---- dump accumulators to LDS gates [row][48] (stride 52) ----
    #pragma unroll
    for (int nt = 0; nt < 3; ++nt)
      #pragma unroll
      for (int ri = 0; ri < 4; ++ri) {
        const int row = wv*16 + (lane >> 4)*4 + ri;
        gates[row*52 + nt*16 + (lane & 15)] = acc[nt][ri];
      }
    __syncthreads();

    // ---- softmax partial sums for mf (q=4) / mi (q=5); exp stored back; publish P ----
    if (tid < 128) {
      const int gi = tid >> 6, r = tid & 63;
      float s = 0.f;
      #pragma unroll
      for (int c = 0; c < 8; ++c) {
        float e = __expf(gates[r*52 + (4+gi)*8 + c] + blds[(4+gi)*8 + c]);
        gates[r*52 + (4+gi)*8 + c] = e;
        s += e;
      }
      ATOM_ST((unsigned*)(a.P + (((size_t)gi) << 12) + r*64 + wg), __float_as_uint(s));
    }
    asm volatile("s_waitcnt vmcnt(0)" ::: "memory");   // per-wave: P stores at coherence point
    __syncthreads();
    if (tid == 0) ATOM_ST(&a.flagP[wg], t+1);
    if (tid < 64) {
      while (ATOM_LD(&a.flagP[tid]) < t+1)
        __builtin_amdgcn_s_sleep(1);
    }
    __syncthreads();

    // ---- prefix over WGs + local cumsum -> final mf/mi in gates ----
    if (tid < 128) {
      const int gi = tid >> 6, r = tid & 63;
      const unsigned long long* pp = (const unsigned long long*)(a.P + (((size_t)gi) << 12) + r*64);
      float offv = 0.f, tot = 0.f;
      #pragma unroll
      for (int j = 0; j < 32; ++j) {
        union { unsigned long long u; float f[2]; } cv;
        cv.u = ATOM_LD(pp + j);
        tot += cv.f[0] + cv.f[1];
        if (2*j     < wg) offv += cv.f[0];
        if (2*j + 1 < wg) offv += cv.f[1];
      }
      const float inv = 1.f / tot;
      float run = offv;
      #pragma unroll
      for (int c = 0; c < 8; ++c) {
        run += gates[r*52 + (4+gi)*8 + c];
        gates[r*52 + (4+gi)*8 + c] = run * inv;
      }
    }
    __syncthreads();

    // ---- elementwise update (one c-pair per thread): c,h; write all_h, Hbf, states ----
    {
      const int r = tid >> 2, cp = tid & 3, c0 = cp*2;
      const float* g = gates + r*52;
      float hv[2], cv2[2];
      #pragma unroll
      for (int u = 0; u < 2; ++u) {
        const int c = c0 + u;
        const float fp = g[c]      + blds[c];
        const float ip = g[8 + c]  + blds[8 + c];
        const float op = g[16 + c] + blds[16 + c];
        const float cp2 = g[24 + c] + blds[24 + c];
        const float mf = g[32 + c];
        const float mi = g[40 + c];
        const float ft = 1.f / (1.f + __expf(-fp));
        const float it = 1.f / (1.f + __expf(-ip));
        const float ot = 1.f / (1.f + __expf(-op));
        const float ch = tanhf(cp2);
        const float w2 = mf * mi;
        const float fh = ft * w2 + (mf - w2);
        const float ih = it * w2 + (mi - w2);
        const float cn = fh * cst[r*8 + c] + ih * ch;
        cst[r*8 + c] = cn;
        cv2[u] = cn;
        hv[u] = ot * cn;
      }
      const int col = wg*8 + c0;
      *(float2*)(a.out + (size_t)t*32768 + r*512 + col) = make_float2(hv[0], hv[1]);
      const unsigned pk = (unsigned)f2bf(hv[0]) | ((unsigned)f2bf(hv[1]) << 16);
      ATOM_ST((unsigned*)(a.Hbf + ((size_t)((t & 1)*64 + r)*512 + col)), pk);
      if (t == slenl[r] - 1) {
        *(float2*)(a.out + (size_t)OUT_SH + r*512 + col) = make_float2(hv[0], hv[1]);
        *(float2*)(a.out + (size_t)OUT_SC + r*512 + col) = make_float2(cv2[0], cv2[1]);
      }
    }
    asm volatile("s_waitcnt vmcnt(0)" ::: "memory");   // per-wave: h stores at coherence point
    __syncthreads();
    if (tid == 0) ATOM_ST(&a.flagH[wg], t+1);
  }
}

// ---------------- host ----------------
extern "C" void kernel_launch(void* const* d_in, const int* in_sizes, int n_in,
                              void* d_out, int out_size, void* d_ws, size_t ws_size,
                              hipStream_t stream) {
  char* ws = (char*)d_ws;

  PrepArgs pa;
  for (int q = 0; q < 6; ++q) {
    pa.W[q]   = (const float*)d_in[3 + 2*q];
    pa.bia[q] = (const float*)d_in[4 + 2*q];
  }
  pa.h0       = (const float*)d_in[1];
  pa.WT       = (unsigned short*)(ws + O_WT);
  pa.bias_all = (float*)(ws + O_BIAS);
  pa.Hbf      = (unsigned short*)(ws + O_HBF);
  pa.flagH    = (int*)(ws + O_FLAGH);
  pa.flagP    = (int*)(ws + O_FLAGP);
  prep_kernel<<<3137, 256, 0, stream>>>(pa);

  const bool ux = (ws_size >= WS_FULL);
  if (ux)
    convx_kernel<<<16384, 256, 0, stream>>>((const float*)d_in[0], (unsigned short*)(ws + O_XBF));

  LstmArgs la;
  la.x        = (const float*)d_in[0];
  la.xbf      = ux ? (const unsigned short*)(ws + O_XBF) : nullptr;
  la.c0       = (const float*)d_in[2];
  la.slen     = (const int*)d_in[15];
  la.WT       = pa.WT;
  la.bias_all = pa.bias_all;
  la.Hbf      = pa.Hbf;
  la.flagH    = pa.flagH;
  la.flagP    = pa.flagP;
  la.P        = (float*)(ws + O_P);
  la.out      = (float*)d_out;

  hipFuncSetAttribute(reinterpret_cast<const void*>(lstm_kernel),
                      hipFuncAttributeMaxDynamicSharedMemorySize, SMEM_TOTAL);
  lstm_kernel<<<NWG, 256, SMEM_TOTAL, stream>>>(la);
}